// Round 2
// baseline (33519.812 us; speedup 1.0000x reference)
//
#include <hip/hip_runtime.h>

#define T_LEN 2048
#define HID   256
#define G4    1024
#define EMBD  128
#define VOCAB 128
#define OUTC  2
#define BSUB  16          // batch rows per chain
#define NCHAIN 8
#define NPART 4           // WGs per chain (hidden-dim split)
#define UPART 64          // hidden units per part
#define CHK   128         // x chunk staged in LDS
#define HS    264         // habuf row stride (bf16): 528 B, 16B-aligned, 2-way-bank-free
#define GS    20          // gbuf inner stride (f32): keeps b128 writes aligned, conflict-free
#define MAGIC 0x50000000  // flag values MAGIC+t; 0xAAAAAAAA poison is negative as int

typedef __bf16 bf16x8 __attribute__((ext_vector_type(8)));
typedef float  f32x4  __attribute__((ext_vector_type(4)));

// P[v][c] = emb[v,:] . W_ih[c,:] + b_ih[c] + b_hh[c]   (512 KB, rebuilt every launch)
__device__ float Pbuf[VOCAB * G4];

__global__ void build_P(const float* __restrict__ emb, const float* __restrict__ W_ih,
                        const float* __restrict__ b_ih, const float* __restrict__ b_hh) {
    const int v = blockIdx.x >> 2;
    const int c = ((blockIdx.x & 3) << 8) + threadIdx.x;
    __shared__ float es[EMBD];
    if (threadIdx.x < EMBD) es[threadIdx.x] = emb[v * EMBD + threadIdx.x];
    __syncthreads();
    const float* wr = W_ih + c * EMBD;
    float acc = 0.f;
    #pragma unroll 8
    for (int e = 0; e < EMBD; ++e) acc += es[e] * wr[e];
    Pbuf[v * G4 + c] = acc + b_ih[c] + b_hh[c];
}

__device__ __forceinline__ float sig_f(float v) {
    return 1.f / (1.f + __expf(-v));
}
__device__ __forceinline__ float tanh_f(float v) {
    float e = __expf(2.f * v);
    return 1.f - 2.f / (e + 1.f);
}

// 32 WGs x 512 thr: WG (chain, part) owns 16 batch rows x 64 hidden units (all 4 gates).
// W_hh slice resident in 64 VGPRs/lane (2 gates x 8 K-frags, bf16). h exchanged via hx
// (global, double-buffered) + per-part monotone flags (device-scope release/acquire).
__global__ __launch_bounds__(512, 2) void lstm_chain(
        const int* __restrict__ x, const float* __restrict__ W_hh,
        const float* __restrict__ fc_W, const float* __restrict__ fc_b,
        __bf16* __restrict__ hx, int* __restrict__ flags, float* __restrict__ out) {
    __shared__ alignas(16) __bf16 habuf[BSUB * HS];      // h_t, A-layout [b][k]
    __shared__ alignas(16) float  gbuf[4 * UPART * GS];  // gate pre-acts [gi][lc][b]
    __shared__ int xch[BSUB * CHK];                      // x index chunk

    const int tid  = threadIdx.x;
    const int w    = tid >> 6;
    const int lane = tid & 63;
    const int l15  = lane & 15;
    const int quad = lane >> 4;
    const int chain = blockIdx.x >> 2;
    const int part  = blockIdx.x & 3;
    const int bbase = chain * BSUB;
    const int gbase = (w >> 2) * 2;        // this wave's first gate (0 or 2)
    const int ut    = w & 3;               // unit sub-tile
    const int cu_l  = ut * 16 + l15;       // local unit col 0..63
    const int cu    = part * UPART + cu_l; // global unit col 0..255

    // --- persistent B fragments: 2 gates x 8 kt x 4 VGPR = 64 VGPRs ---
    // B[k = kt*32 + quad*8 + j][n = gate_col] = W_hh[gate_col][k]
    bf16x8 Bf[2][8];
    #pragma unroll
    for (int g = 0; g < 2; ++g) {
        const float* wr = W_hh + (size_t)((gbase + g) * HID + cu) * HID;
        #pragma unroll
        for (int kt = 0; kt < 8; ++kt) {
            const float* p = wr + kt * 32 + quad * 8;
            bf16x8 bv;
            #pragma unroll
            for (int j = 0; j < 8; ++j) bv[j] = (__bf16)p[j];
            Bf[g][kt] = bv;
        }
    }

    // gate-math thread mapping: (batch gb, unit pair lc0) — fixed across steps, owns c
    const int gb  = tid & 15;
    const int lc0 = (tid >> 4) * 2;
    float cst[2] = {0.f, 0.f};

    for (int i = tid; i < BSUB * HS; i += 512) habuf[i] = (__bf16)0.f;  // h_0 = 0
    __syncthreads();

    #pragma unroll 1
    for (int t = 0; t < T_LEN; ++t) {
        const int tt = t & (CHK - 1);
        if (tt == 0) {
            __syncthreads();  // prior readers of xch done
            for (int i = tid; i < BSUB * CHK; i += 512) {
                const int bi = i >> 7, tj = i & (CHK - 1);
                xch[i] = x[(bbase + bi) * T_LEN + t + tj];
            }
            __syncthreads();
        }

        // xg gather from Pbuf (L2-hot); issued before the spin so it overlaps the wait
        float xg[2][4];
        #pragma unroll
        for (int u = 0; u < 4; ++u) {
            const int xv = xch[(quad * 4 + u) * CHK + tt];
            const float* pb = Pbuf + (size_t)xv * G4 + cu;
            xg[0][u] = pb[gbase * HID];
            xg[1][u] = pb[(gbase + 1) * HID];
        }

        if (t > 0) {
            const int want = MAGIC + t;
            if (tid < NPART) {
                while (__hip_atomic_load(&flags[chain * NPART + tid], __ATOMIC_RELAXED,
                                         __HIP_MEMORY_SCOPE_AGENT) < want)
                    __builtin_amdgcn_s_sleep(1);
            }
            __syncthreads();
            __threadfence();  // acquire: invalidate caches before reading partners' h
            const __bf16* src = hx + ((((size_t)(t & 1)) * NCHAIN + chain) * BSUB + (tid >> 5)) * HID
                              + (tid & 31) * 8;
            const bf16x8 hv = *(const bf16x8*)src;
            *(bf16x8*)(habuf + (tid >> 5) * HS + (tid & 31) * 8) = hv;
        }
        __syncthreads();  // habuf ready

        // --- MFMA phase: [16 batch x 32 gate-cols] += h_t[16x256] . W_hh_slice ---
        bf16x8 a[8];
        #pragma unroll
        for (int kt = 0; kt < 8; ++kt)
            a[kt] = *(const bf16x8*)(habuf + l15 * HS + kt * 32 + quad * 8);

        f32x4 acc[2];
        #pragma unroll
        for (int g = 0; g < 2; ++g) {
            f32x4 v;
            v[0] = xg[g][0]; v[1] = xg[g][1]; v[2] = xg[g][2]; v[3] = xg[g][3];
            acc[g] = v;
        }
        #pragma unroll
        for (int kt = 0; kt < 8; ++kt) {
            acc[0] = __builtin_amdgcn_mfma_f32_16x16x32_bf16(a[kt], Bf[0][kt], acc[0], 0, 0, 0);
            acc[1] = __builtin_amdgcn_mfma_f32_16x16x32_bf16(a[kt], Bf[1][kt], acc[1], 0, 0, 0);
        }

        #pragma unroll
        for (int g = 0; g < 2; ++g)
            *(f32x4*)(gbuf + ((gbase + g) * UPART + cu_l) * GS + quad * 4) = acc[g];
        __syncthreads();  // gbuf ready

        // --- gate math: each thread owns 2 (unit, batch) cells ---
        __bf16 hp[2];
        #pragma unroll
        for (int e = 0; e < 2; ++e) {
            const int lc = lc0 + e;
            const float gi_ = gbuf[(0 * UPART + lc) * GS + gb];
            const float gf  = gbuf[(1 * UPART + lc) * GS + gb];
            const float gg  = gbuf[(2 * UPART + lc) * GS + gb];
            const float go  = gbuf[(3 * UPART + lc) * GS + gb];
            const float is = sig_f(gi_);
            const float fs = sig_f(gf);
            const float gt = tanh_f(gg);
            const float os = sig_f(go);
            const float c = fs * cst[e] + is * gt;
            cst[e] = c;
            hp[e] = (__bf16)(os * tanh_f(c));
        }
        // publish h_{t+1} part to hx[(t+1)&1]
        {
            __bf16* dst = hx + ((((size_t)((t + 1) & 1)) * NCHAIN + chain) * BSUB + gb) * HID
                        + part * UPART + lc0;
            union { __bf16 h2[2]; unsigned int u32; } pk;
            pk.h2[0] = hp[0]; pk.h2[1] = hp[1];
            *(unsigned int*)dst = pk.u32;
        }
        __threadfence();   // release: own stores visible device-wide
        __syncthreads();   // all threads' fences done
        if (tid == 0)
            __hip_atomic_store(&flags[chain * NPART + part], MAGIC + t + 1,
                               __ATOMIC_RELEASE, __HIP_MEMORY_SCOPE_AGENT);
    }

    // --- FC epilogue: part 0 of each chain reads final h (hx buf 0 = hx[(T)&1]) ---
    if (part == 0) {
        const int want = MAGIC + T_LEN;
        if (tid < NPART) {
            while (__hip_atomic_load(&flags[chain * NPART + tid], __ATOMIC_RELAXED,
                                     __HIP_MEMORY_SCOPE_AGENT) < want)
                __builtin_amdgcn_s_sleep(1);
        }
        __syncthreads();
        __threadfence();
        if (tid < BSUB * OUTC) {
            const int b = tid >> 1, o = tid & 1;
            const __bf16* hr = hx + ((size_t)chain * BSUB + b) * HID;  // buf 0
            float s = fc_b[o];
            #pragma unroll 8
            for (int j = 0; j < HID; ++j) s += (float)hr[j] * fc_W[o * HID + j];
            out[(bbase + b) * OUTC + o] = s;
        }
    }
}

extern "C" void kernel_launch(void* const* d_in, const int* in_sizes, int n_in,
                              void* d_out, int out_size, void* d_ws, size_t ws_size,
                              hipStream_t stream) {
    const int*   x    = (const int*)  d_in[0];
    const float* emb  = (const float*)d_in[1];
    const float* W_ih = (const float*)d_in[2];
    const float* W_hh = (const float*)d_in[3];
    const float* b_ih = (const float*)d_in[4];
    const float* b_hh = (const float*)d_in[5];
    const float* fc_W = (const float*)d_in[6];
    const float* fc_b = (const float*)d_in[7];
    float* out = (float*)d_out;

    // workspace: hx double buffer [2][8][16][256] bf16 = 128 KB, then flags [8][4] int.
    __bf16* hx  = (__bf16*)d_ws;
    int* flags  = (int*)((char*)d_ws + (size_t)2 * NCHAIN * BSUB * HID * sizeof(__bf16));

    build_P<<<dim3(VOCAB * 4), dim3(256), 0, stream>>>(emb, W_ih, b_ih, b_hh);
    lstm_chain<<<dim3(NCHAIN * NPART), dim3(512), 0, stream>>>(x, W_hh, fc_W, fc_b,
                                                               hx, flags, out);
}

// Round 3
// 6994.220 us; speedup vs baseline: 4.7925x; 4.7925x over previous
//
#include <hip/hip_runtime.h>

#define T_LEN 2048
#define HID   256
#define G4    1024
#define EMBD  128
#define VOCAB 128
#define OUTC  2
#define BSUB  16          // batch rows per chain
#define NCHAIN 8
#define CHK   64          // x chunk staged in LDS
#define HSB   272         // habuf row stride in BYTES (i8): 256 + 16 pad, 16B-aligned

typedef int   i32x4 __attribute__((ext_vector_type(4)));

// Device-global scratch rebuilt every launch (no fences needed: kernel-boundary coherence).
__device__ float Pbuf[VOCAB * G4];                    // x-projection LUT: emb@W_ih^T + biases
__device__ __align__(16) signed char Wqb[G4 * HID];   // int8-quantized W_hh, row-major [gatecol][k]
__device__ float Winv[G4];                            // per-row dequant factor m/(127*127)

__global__ void build_P(const float* __restrict__ emb, const float* __restrict__ W_ih,
                        const float* __restrict__ b_ih, const float* __restrict__ b_hh) {
    const int v = blockIdx.x >> 2;
    const int c = ((blockIdx.x & 3) << 8) + threadIdx.x;
    __shared__ float es[EMBD];
    if (threadIdx.x < EMBD) es[threadIdx.x] = emb[v * EMBD + threadIdx.x];
    __syncthreads();
    const float* wr = W_ih + c * EMBD;
    float acc = 0.f;
    #pragma unroll 8
    for (int e = 0; e < EMBD; ++e) acc += es[e] * wr[e];
    Pbuf[v * G4 + c] = acc + b_ih[c] + b_hh[c];
}

// per-row symmetric int8 quantization of W_hh (1024 rows x 256)
__global__ void quant_W(const float* __restrict__ W_hh) {
    const int row = blockIdx.x;
    const int k   = threadIdx.x;
    __shared__ float red[4];
    const float wv = W_hh[row * HID + k];
    float a = fabsf(wv);
    #pragma unroll
    for (int o = 32; o > 0; o >>= 1) a = fmaxf(a, __shfl_down(a, o, 64));
    if ((k & 63) == 0) red[k >> 6] = a;
    __syncthreads();
    const float m = fmaxf(fmaxf(fmaxf(red[0], red[1]), red[2]), fmaxf(red[3], 1e-30f));
    Wqb[row * HID + k] = (signed char)(int)rintf(wv * (127.f / m));
    if (k == 0) Winv[row] = m * (1.f / (127.f * 127.f));
}

__device__ __forceinline__ float sig_f(float v) {
    return 1.f / (1.f + __expf(-v));
}
__device__ __forceinline__ float tanh_f(float v) {
    float e = __expf(2.f * v);
    return 1.f - 2.f / (e + 1.f);
}

// 8 WGs x 512 thr: one WG = one chain of 16 batch rows, whole T loop on one CU.
// int8 W_hh resident in 128 VGPRs/lane; h int8 via LDS ping-pong; ONE barrier per step;
// no global traffic in the loop except L2-hot Pbuf gathers (prefetched one step ahead).
__global__ __launch_bounds__(512, 2) void lstm_chain(
        const int* __restrict__ x, const float* __restrict__ fc_W,
        const float* __restrict__ fc_b, float* __restrict__ out) {
    __shared__ __align__(16) signed char habuf[2][BSUB * HSB];  // h_q ping-pong [b][k] i8
    __shared__ int   xch[BSUB * CHK];                           // x index chunk
    __shared__ float hfin[BSUB * HID];                          // final h (f32) for FC

    const int tid  = threadIdx.x;
    const int w    = tid >> 6;       // wave 0..7: owns units [32w, 32w+32), all 4 gates
    const int lane = tid & 63;
    const int l15  = lane & 15;
    const int quad = lane >> 4;
    const int bbase = blockIdx.x * BSUB;
    const int ub    = w * 32;

    // --- persistent int8 B fragments: 2 tiles x 4 gates x 4 K-chunks x 4 VGPR = 128 VGPRs ---
    // B[k = kt*64 + quad*16 + j][n = l15] = Wq[g*256 + ub + nt*16 + l15][k]
    i32x4 Bf[2][4][4];
    float winvv[2][4];
    #pragma unroll
    for (int nt = 0; nt < 2; ++nt) {
        #pragma unroll
        for (int g = 0; g < 4; ++g) {
            const int row = g * HID + ub + nt * 16 + l15;
            const signed char* wr = Wqb + (size_t)row * HID;
            winvv[nt][g] = Winv[row];
            #pragma unroll
            for (int kt = 0; kt < 4; ++kt)
                Bf[nt][g][kt] = *(const i32x4*)(wr + kt * 64 + quad * 16);
        }
    }

    // zero h buffers (h_0 = 0)
    for (int i = tid; i < 2 * BSUB * HSB; i += 512) ((signed char*)habuf)[i] = 0;

    float cst[2][4];                 // cell state: (tile nt, row u) for cell (quad*4+u, ub+nt*16+l15)
    #pragma unroll
    for (int nt = 0; nt < 2; ++nt)
        #pragma unroll
        for (int u = 0; u < 4; ++u) cst[nt][u] = 0.f;

    float xgv[2][4][4];              // xg for current step: [nt][gate][u]

    #pragma unroll 1
    for (int t = 0; t < T_LEN; ++t) {
        const int tt = t & (CHK - 1);
        if (tt == 0) {
            // refill x chunk (prev step's end barrier protects old readers; t=0: pre-loop state)
            for (int i = tid; i < BSUB * CHK; i += 512)
                xch[i] = x[(bbase + (i >> 6)) * T_LEN + t + (i & (CHK - 1))];
            __syncthreads();
            // chunk boundary: xg for this step wasn't prefetched
            #pragma unroll
            for (int u = 0; u < 4; ++u) {
                const int xv = xch[(quad * 4 + u) * CHK + tt];
                const float* pb = Pbuf + (size_t)xv * G4 + ub + l15;
                #pragma unroll
                for (int nt = 0; nt < 2; ++nt)
                    #pragma unroll
                    for (int g = 0; g < 4; ++g)
                        xgv[nt][g][u] = pb[g * HID + nt * 16];
            }
        }

        // A fragments: h_q from LDS, A[m = l15][k = kt*64 + quad*16 + j]
        const signed char* hb = habuf[t & 1];
        i32x4 af[4];
        #pragma unroll
        for (int kt = 0; kt < 4; ++kt)
            af[kt] = *(const i32x4*)(hb + l15 * HSB + kt * 64 + quad * 16);

        i32x4 acc[2][4];
        #pragma unroll
        for (int nt = 0; nt < 2; ++nt)
            #pragma unroll
            for (int g = 0; g < 4; ++g) {
                i32x4 z = {0, 0, 0, 0};
                acc[nt][g] = z;
            }

        // 32 MFMAs: 8 independent (nt,g) chains x 4 K-steps
        #pragma unroll
        for (int kt = 0; kt < 4; ++kt)
            #pragma unroll
            for (int nt = 0; nt < 2; ++nt)
                #pragma unroll
                for (int g = 0; g < 4; ++g)
                    acc[nt][g] = __builtin_amdgcn_mfma_i32_16x16x64_i8(
                        af[kt], Bf[nt][g][kt], acc[nt][g], 0, 0, 0);

        // dequant + gate math + state update, all in-register (C layout == cell ownership)
        signed char* hn = habuf[(t + 1) & 1];
        #pragma unroll
        for (int nt = 0; nt < 2; ++nt) {
            const int col = ub + nt * 16 + l15;
            #pragma unroll
            for (int u = 0; u < 4; ++u) {
                const float gi_ = (float)acc[nt][0][u] * winvv[nt][0] + xgv[nt][0][u];
                const float gf_ = (float)acc[nt][1][u] * winvv[nt][1] + xgv[nt][1][u];
                const float gg_ = (float)acc[nt][2][u] * winvv[nt][2] + xgv[nt][2][u];
                const float go_ = (float)acc[nt][3][u] * winvv[nt][3] + xgv[nt][3][u];
                const float is = sig_f(gi_);
                const float fs = sig_f(gf_);
                const float gt = tanh_f(gg_);
                const float os = sig_f(go_);
                const float c  = fs * cst[nt][u] + is * gt;
                cst[nt][u] = c;
                const float h = os * tanh_f(c);
                hn[(quad * 4 + u) * HSB + col] = (signed char)(int)rintf(h * 127.f);
                if (t == T_LEN - 1) hfin[(quad * 4 + u) * HID + col] = h;
            }
        }

        // prefetch next step's xg from L2-hot Pbuf (lands during barrier + next MFMA phase)
        if (tt != CHK - 1) {
            #pragma unroll
            for (int u = 0; u < 4; ++u) {
                const int xv = xch[(quad * 4 + u) * CHK + tt + 1];
                const float* pb = Pbuf + (size_t)xv * G4 + ub + l15;
                #pragma unroll
                for (int nt = 0; nt < 2; ++nt)
                    #pragma unroll
                    for (int g = 0; g < 4; ++g)
                        xgv[nt][g][u] = pb[g * HID + nt * 16];
            }
        }

        __syncthreads();  // h_{t+1} published; also protects xch refill at next chunk start
    }

    // --- FC epilogue: logits[b,o] = hT[b,:] . fc_W[o,:] + fc_b[o] ---
    if (tid < BSUB * OUTC) {
        const int b = tid >> 1, o = tid & 1;
        float s = fc_b[o];
        #pragma unroll 8
        for (int j = 0; j < HID; ++j) s += hfin[b * HID + j] * fc_W[o * HID + j];
        out[(bbase + b) * OUTC + o] = s;
    }
}

extern "C" void kernel_launch(void* const* d_in, const int* in_sizes, int n_in,
                              void* d_out, int out_size, void* d_ws, size_t ws_size,
                              hipStream_t stream) {
    const int*   x    = (const int*)  d_in[0];
    const float* emb  = (const float*)d_in[1];
    const float* W_ih = (const float*)d_in[2];
    const float* W_hh = (const float*)d_in[3];
    const float* b_ih = (const float*)d_in[4];
    const float* b_hh = (const float*)d_in[5];
    const float* fc_W = (const float*)d_in[6];
    const float* fc_b = (const float*)d_in[7];
    float* out = (float*)d_out;
    (void)d_ws; (void)ws_size;

    build_P<<<dim3(VOCAB * 4), dim3(256), 0, stream>>>(emb, W_ih, b_ih, b_hh);
    quant_W<<<dim3(G4), dim3(HID), 0, stream>>>(W_hh);
    lstm_chain<<<dim3(NCHAIN), dim3(512), 0, stream>>>(x, fc_W, fc_b, out);
}

// Round 4
// 3914.605 us; speedup vs baseline: 8.5628x; 1.7867x over previous
//
#include <hip/hip_runtime.h>

#define T_LEN 2048
#define HID   256
#define G4    1024
#define EMBD  128
#define VOCAB 128
#define OUTC  2
#define BSUB  16          // batch rows per chain
#define NCHAIN 8
#define CHK   64          // x chunk staged in LDS
#define HSB   272         // habuf row stride in BYTES (i8): 256 + 16 pad, 16B-aligned
#define LOG2E 1.44269504088896340736f

typedef int i32x4 __attribute__((ext_vector_type(4)));

// Device-global scratch rebuilt every launch (kernel-boundary coherence, no fences).
__device__ float Pbuf[VOCAB * G4];                    // x-proj LUT, PRE-SCALED by -log2e / -2log2e per gate
__device__ __align__(16) signed char Wqb[G4 * HID];   // int8 W_hh, row-major [gatecol][k]
__device__ float Winv[G4];                            // m/(127^2) * per-gate exp2 scale

__global__ void build_P(const float* __restrict__ emb, const float* __restrict__ W_ih,
                        const float* __restrict__ b_ih, const float* __restrict__ b_hh) {
    const int v = blockIdx.x >> 2;
    const int c = ((blockIdx.x & 3) << 8) + threadIdx.x;
    __shared__ float es[EMBD];
    if (threadIdx.x < EMBD) es[threadIdx.x] = emb[v * EMBD + threadIdx.x];
    __syncthreads();
    const float* wr = W_ih + c * EMBD;
    float acc = 0.f;
    #pragma unroll 8
    for (int e = 0; e < EMBD; ++e) acc += es[e] * wr[e];
    // gate 2 (g) feeds tanh -> scale -2log2e; gates i,f,o feed sigmoid -> -log2e
    const float ks = ((c >> 8) == 2) ? (-2.f * LOG2E) : (-LOG2E);
    Pbuf[v * G4 + c] = (acc + b_ih[c] + b_hh[c]) * ks;
}

// per-row symmetric int8 quantization of W_hh (1024 rows x 256)
__global__ void quant_W(const float* __restrict__ W_hh) {
    const int row = blockIdx.x;
    const int k   = threadIdx.x;
    __shared__ float red[4];
    const float wv = W_hh[row * HID + k];
    float a = fabsf(wv);
    #pragma unroll
    for (int o = 32; o > 0; o >>= 1) a = fmaxf(a, __shfl_down(a, o, 64));
    if ((k & 63) == 0) red[k >> 6] = a;
    __syncthreads();
    const float m = fmaxf(fmaxf(fmaxf(red[0], red[1]), red[2]), fmaxf(red[3], 1e-30f));
    Wqb[row * HID + k] = (signed char)(int)rintf(wv * (127.f / m));
    const float ks = ((row >> 8) == 2) ? (-2.f * LOG2E) : (-LOG2E);
    if (k == 0) Winv[row] = m * (1.f / (127.f * 127.f)) * ks;
}

// r = 1/(1+2^p).  With p = -x*log2e this is sigmoid(x); tanh(x) = 2*r(-2x*log2e)-1.
__device__ __forceinline__ float sig_p(float p) {
    return __builtin_amdgcn_rcpf(1.f + __builtin_amdgcn_exp2f(p));
}

// 8 WGs x 512 thr: one WG = one chain of 16 batch rows, whole T loop on one CU.
// int8 W_hh resident (unified VGPR/AGPR file); h int8 LDS ping-pong; 1 barrier/step.
__global__ __launch_bounds__(512, 2) void lstm_chain(
        const int* __restrict__ x, const float* __restrict__ fc_W,
        const float* __restrict__ fc_b, float* __restrict__ out) {
    __shared__ __align__(16) signed char habuf[2][BSUB * HSB];
    __shared__ int   xch[BSUB * CHK];
    __shared__ float hfin[BSUB * HID];

    const int tid  = threadIdx.x;
    const int w    = tid >> 6;       // wave 0..7: owns units [32w, 32w+32), all 4 gates
    const int lane = tid & 63;
    const int l15  = lane & 15;
    const int quad = lane >> 4;
    const int bbase = blockIdx.x * BSUB;
    const int ub    = w * 32;

    // persistent int8 B fragments: 2 tiles x 4 gates x 4 K-chunks x 4 regs = 128 regs
    i32x4 Bf[2][4][4];
    float winvv[2][4];
    #pragma unroll
    for (int nt = 0; nt < 2; ++nt) {
        #pragma unroll
        for (int g = 0; g < 4; ++g) {
            const int row = g * HID + ub + nt * 16 + l15;
            const signed char* wr = Wqb + (size_t)row * HID;
            winvv[nt][g] = Winv[row];
            #pragma unroll
            for (int kt = 0; kt < 4; ++kt)
                Bf[nt][g][kt] = *(const i32x4*)(wr + kt * 64 + quad * 16);
        }
    }

    for (int i = tid; i < BSUB * HSB; i += 512) habuf[0][i] = 0;   // h_0 = 0

    float cst[2][4];
    #pragma unroll
    for (int nt = 0; nt < 2; ++nt)
        #pragma unroll
        for (int u = 0; u < 4; ++u) cst[nt][u] = 0.f;

    float xgv[2][4][4];              // pre-scaled xg for the current step

#define GATHER(TT)                                                            \
    {                                                                         \
        _Pragma("unroll")                                                     \
        for (int u = 0; u < 4; ++u) {                                         \
            const int xv = xch[(quad * 4 + u) * CHK + (TT)];                  \
            const float* pb = Pbuf + (size_t)xv * G4 + ub + l15;              \
            _Pragma("unroll")                                                 \
            for (int nt = 0; nt < 2; ++nt)                                    \
                _Pragma("unroll")                                             \
                for (int g = 0; g < 4; ++g)                                   \
                    xgv[nt][g][u] = pb[g * HID + nt * 16];                    \
        }                                                                     \
    }

#define STEP(T, HB, HN)                                                       \
    {                                                                         \
        const int t  = (T);                                                   \
        const int tt = t & (CHK - 1);                                         \
        if (tt == 0) {                                                        \
            for (int i = tid; i < BSUB * CHK; i += 512)                       \
                xch[i] = x[(bbase + (i >> 6)) * T_LEN + t + (i & (CHK - 1))]; \
            __syncthreads();                                                  \
            GATHER(0);                                                        \
        }                                                                     \
        i32x4 af[4];                                                          \
        _Pragma("unroll")                                                     \
        for (int kt = 0; kt < 4; ++kt)                                        \
            af[kt] = *(const i32x4*)((HB) + l15 * HSB + kt * 64 + quad * 16); \
        i32x4 acc[2][4];                                                      \
        _Pragma("unroll")                                                     \
        for (int nt = 0; nt < 2; ++nt)                                        \
            _Pragma("unroll")                                                 \
            for (int g = 0; g < 4; ++g) {                                     \
                i32x4 z = {0, 0, 0, 0};                                       \
                acc[nt][g] = z;                                               \
            }                                                                 \
        _Pragma("unroll")                                                     \
        for (int kt = 0; kt < 4; ++kt)                                        \
            _Pragma("unroll")                                                 \
            for (int nt = 0; nt < 2; ++nt)                                    \
                _Pragma("unroll")                                             \
                for (int g = 0; g < 4; ++g)                                   \
                    acc[nt][g] = __builtin_amdgcn_mfma_i32_16x16x64_i8(       \
                        af[kt], Bf[nt][g][kt], acc[nt][g], 0, 0, 0);          \
        _Pragma("unroll")                                                     \
        for (int nt = 0; nt < 2; ++nt) {                                      \
            const int col = ub + nt * 16 + l15;                               \
            _Pragma("unroll")                                                 \
            for (int u = 0; u < 4; ++u) {                                     \
                const float pi = fmaf((float)acc[nt][0][u], winvv[nt][0], xgv[nt][0][u]); \
                const float pf = fmaf((float)acc[nt][1][u], winvv[nt][1], xgv[nt][1][u]); \
                const float pg = fmaf((float)acc[nt][2][u], winvv[nt][2], xgv[nt][2][u]); \
                const float po = fmaf((float)acc[nt][3][u], winvv[nt][3], xgv[nt][3][u]); \
                const float is = sig_p(pi);                                   \
                const float fs = sig_p(pf);                                   \
                const float gt = fmaf(2.f, sig_p(pg), -1.f);                  \
                const float os = sig_p(po);                                   \
                const float c  = fmaf(fs, cst[nt][u], is * gt);               \
                cst[nt][u] = c;                                               \
                const float r2    = sig_p(c * (-2.f * LOG2E));                \
                const float th127 = fmaf(254.f, r2, -127.f);                  \
                const float hq    = th127 * os;                               \
                (HN)[(quad * 4 + u) * HSB + col] = (signed char)(int)rintf(hq); \
                if (t == T_LEN - 1)                                           \
                    hfin[(quad * 4 + u) * HID + col] = hq * (1.f / 127.f);    \
            }                                                                 \
        }                                                                     \
        if (tt != CHK - 1) GATHER(tt + 1);                                    \
        __syncthreads();                                                      \
    }

    #pragma unroll 1
    for (int t2 = 0; t2 < T_LEN; t2 += 2) {
        STEP(t2,     habuf[0], habuf[1]);
        STEP(t2 + 1, habuf[1], habuf[0]);
    }
#undef STEP
#undef GATHER

    // FC epilogue: logits[b,o] = hT[b,:] . fc_W[o,:] + fc_b[o]
    if (tid < BSUB * OUTC) {
        const int b = tid >> 1, o = tid & 1;
        float s = fc_b[o];
        #pragma unroll 8
        for (int j = 0; j < HID; ++j) s += hfin[b * HID + j] * fc_W[o * HID + j];
        out[(bbase + b) * OUTC + o] = s;
    }
}

extern "C" void kernel_launch(void* const* d_in, const int* in_sizes, int n_in,
                              void* d_out, int out_size, void* d_ws, size_t ws_size,
                              hipStream_t stream) {
    const int*   x    = (const int*)  d_in[0];
    const float* emb  = (const float*)d_in[1];
    const float* W_ih = (const float*)d_in[2];
    const float* W_hh = (const float*)d_in[3];
    const float* b_ih = (const float*)d_in[4];
    const float* b_hh = (const float*)d_in[5];
    const float* fc_W = (const float*)d_in[6];
    const float* fc_b = (const float*)d_in[7];
    float* out = (float*)d_out;
    (void)d_ws; (void)ws_size;

    build_P<<<dim3(VOCAB * 4), dim3(256), 0, stream>>>(emb, W_ih, b_ih, b_hh);
    quant_W<<<dim3(G4), dim3(HID), 0, stream>>>(W_hh);
    lstm_chain<<<dim3(NCHAIN), dim3(512), 0, stream>>>(x, fc_W, fc_b, out);
}

// Round 5
// 1725.738 us; speedup vs baseline: 19.4235x; 2.2684x over previous
//
#include <hip/hip_runtime.h>

#define T_LEN 2048
#define HID   256
#define G4    1024
#define EMBD  128
#define VOCAB 128
#define OUTC  2
#define BSUB  4           // batch rows per chain
#define NCHAIN 32
#define CHK   64          // x chunk staged in LDS
#define HSB   288         // habuf row stride BYTES (i8): bank shift 8/row -> conflict-free
#define LOG2E 1.44269504088896340736f

typedef int i32x4 __attribute__((ext_vector_type(4)));

// Device-global scratch rebuilt every launch (kernel-boundary coherence, no fences).
__device__ float Pbuf[VOCAB * G4];                    // x-proj LUT, pre-scaled by -log2e / -2log2e
__device__ __align__(16) signed char Wqb[G4 * HID];   // int8 W_hh, row-major [gatecol][k]
__device__ float Winv[G4];                            // m/(127^2) * per-gate exp2 scale

__global__ void build_P(const float* __restrict__ emb, const float* __restrict__ W_ih,
                        const float* __restrict__ b_ih, const float* __restrict__ b_hh) {
    const int v = blockIdx.x >> 2;
    const int c = ((blockIdx.x & 3) << 8) + threadIdx.x;
    __shared__ float es[EMBD];
    if (threadIdx.x < EMBD) es[threadIdx.x] = emb[v * EMBD + threadIdx.x];
    __syncthreads();
    const float* wr = W_ih + c * EMBD;
    float acc = 0.f;
    #pragma unroll 8
    for (int e = 0; e < EMBD; ++e) acc += es[e] * wr[e];
    const float ks = ((c >> 8) == 2) ? (-2.f * LOG2E) : (-LOG2E);
    Pbuf[v * G4 + c] = (acc + b_ih[c] + b_hh[c]) * ks;
}

// per-row symmetric int8 quantization of W_hh (1024 rows x 256)
__global__ void quant_W(const float* __restrict__ W_hh) {
    const int row = blockIdx.x;
    const int k   = threadIdx.x;
    __shared__ float red[4];
    const float wv = W_hh[row * HID + k];
    float a = fabsf(wv);
    #pragma unroll
    for (int o = 32; o > 0; o >>= 1) a = fmaxf(a, __shfl_down(a, o, 64));
    if ((k & 63) == 0) red[k >> 6] = a;
    __syncthreads();
    const float m = fmaxf(fmaxf(fmaxf(red[0], red[1]), red[2]), fmaxf(red[3], 1e-30f));
    Wqb[row * HID + k] = (signed char)(int)rintf(wv * (127.f / m));
    const float ks = ((row >> 8) == 2) ? (-2.f * LOG2E) : (-LOG2E);
    if (k == 0) Winv[row] = m * (1.f / (127.f * 127.f)) * ks;
}

// r = 1/(1+2^p).  p = -x*log2e -> sigmoid(x); tanh(x) = 2*r(-2x*log2e)-1.
__device__ __forceinline__ float sig_p(float p) {
    return __builtin_amdgcn_rcpf(1.f + __builtin_amdgcn_exp2f(p));
}

// 32 WGs x 512 thr: one WG = one chain of 4 batch rows, whole T loop on one CU.
// int8 W_hh resident (128 regs/lane); h replicated 4x in MFMA M-dim so every lane
// owns exactly 2 cells (batch=quad, cols ub+l15 / ub+16+l15) with gates at u=0.
__global__ __launch_bounds__(512, 2) void lstm_chain(
        const int* __restrict__ x, const float* __restrict__ fc_W,
        const float* __restrict__ fc_b, float* __restrict__ out) {
    __shared__ __align__(16) signed char habuf[2][BSUB * HSB];
    __shared__ int   xch[BSUB * CHK];
    __shared__ float hfin[BSUB * HID];

    const int tid  = threadIdx.x;
    const int w    = tid >> 6;       // wave 0..7: owns units [32w, 32w+32), all 4 gates
    const int lane = tid & 63;
    const int l15  = lane & 15;
    const int quad = lane >> 4;      // == this lane's batch row
    const int bbase = blockIdx.x * BSUB;
    const int ub    = w * 32;

    // persistent int8 B fragments: 2 tiles x 4 gates x 4 K-chunks x 4 regs = 128 regs
    i32x4 Bf[2][4][4];
    float winvv[2][4];
    #pragma unroll
    for (int nt = 0; nt < 2; ++nt) {
        #pragma unroll
        for (int g = 0; g < 4; ++g) {
            const int row = g * HID + ub + nt * 16 + l15;
            const signed char* wr = Wqb + (size_t)row * HID;
            winvv[nt][g] = Winv[row];
            #pragma unroll
            for (int kt = 0; kt < 4; ++kt)
                Bf[nt][g][kt] = *(const i32x4*)(wr + kt * 64 + quad * 16);
        }
    }

    for (int i = tid; i < BSUB * HSB; i += 512) habuf[0][i] = 0;   // h_0 = 0

    float cst[2] = {0.f, 0.f};       // cell state: nt=0 -> col ub+l15, nt=1 -> col ub+16+l15
    float xgv[2][4];                 // pre-scaled xg for current step [nt][gate]

#define GATHER(TT)                                                            \
    {                                                                         \
        const int xv = xch[quad * CHK + (TT)];                                \
        const float* pb = Pbuf + (size_t)xv * G4 + ub + l15;                  \
        _Pragma("unroll")                                                     \
        for (int nt = 0; nt < 2; ++nt)                                        \
            _Pragma("unroll")                                                 \
            for (int g = 0; g < 4; ++g)                                       \
                xgv[nt][g] = pb[g * HID + nt * 16];                           \
    }

#define STEP(T, HB, HN)                                                       \
    {                                                                         \
        const int t  = (T);                                                   \
        const int tt = t & (CHK - 1);                                         \
        if (tt == 0) {                                                        \
            for (int i = tid; i < BSUB * CHK; i += 512)                       \
                xch[i] = x[(bbase + (i >> 6)) * T_LEN + t + (i & (CHK - 1))]; \
            __syncthreads();                                                  \
            GATHER(0);                                                        \
        }                                                                     \
        i32x4 af[4];                                                          \
        _Pragma("unroll")                                                     \
        for (int kt = 0; kt < 4; ++kt)                                        \
            af[kt] = *(const i32x4*)((HB) + (l15 >> 2) * HSB + kt * 64 + quad * 16); \
        i32x4 acc[2][4];                                                      \
        _Pragma("unroll")                                                     \
        for (int nt = 0; nt < 2; ++nt)                                        \
            _Pragma("unroll")                                                 \
            for (int g = 0; g < 4; ++g) {                                     \
                i32x4 z = {0, 0, 0, 0};                                       \
                acc[nt][g] = z;                                               \
            }                                                                 \
        _Pragma("unroll")                                                     \
        for (int kt = 0; kt < 4; ++kt)                                        \
            _Pragma("unroll")                                                 \
            for (int nt = 0; nt < 2; ++nt)                                    \
                _Pragma("unroll")                                             \
                for (int g = 0; g < 4; ++g)                                   \
                    acc[nt][g] = __builtin_amdgcn_mfma_i32_16x16x64_i8(       \
                        af[kt], Bf[nt][g][kt], acc[nt][g], 0, 0, 0);          \
        _Pragma("unroll")                                                     \
        for (int nt = 0; nt < 2; ++nt) {                                      \
            const int col = ub + nt * 16 + l15;                               \
            const float pi = fmaf((float)acc[nt][0][0], winvv[nt][0], xgv[nt][0]); \
            const float pf = fmaf((float)acc[nt][1][0], winvv[nt][1], xgv[nt][1]); \
            const float pg = fmaf((float)acc[nt][2][0], winvv[nt][2], xgv[nt][2]); \
            const float po = fmaf((float)acc[nt][3][0], winvv[nt][3], xgv[nt][3]); \
            const float is = sig_p(pi);                                       \
            const float fs = sig_p(pf);                                       \
            const float gt = fmaf(2.f, sig_p(pg), -1.f);                      \
            const float os = sig_p(po);                                       \
            const float c  = fmaf(fs, cst[nt], is * gt);                      \
            cst[nt] = c;                                                      \
            const float r2    = sig_p(c * (-2.f * LOG2E));                    \
            const float th127 = fmaf(254.f, r2, -127.f);                      \
            const float hq    = th127 * os;                                   \
            (HN)[quad * HSB + col] = (signed char)(int)rintf(hq);             \
            if (t == T_LEN - 1)                                               \
                hfin[quad * HID + col] = hq * (1.f / 127.f);                  \
        }                                                                     \
        if (tt != CHK - 1) GATHER(tt + 1);                                    \
        __syncthreads();                                                      \
    }

    #pragma unroll 1
    for (int t2 = 0; t2 < T_LEN; t2 += 2) {
        STEP(t2,     habuf[0], habuf[1]);
        STEP(t2 + 1, habuf[1], habuf[0]);
    }
#undef STEP
#undef GATHER

    // FC epilogue: logits[b,o] = hT[b,:] . fc_W[o,:] + fc_b[o]
    if (tid < BSUB * OUTC) {
        const int b = tid >> 1, o = tid & 1;
        float s = fc_b[o];
        #pragma unroll 8
        for (int j = 0; j < HID; ++j) s += hfin[b * HID + j] * fc_W[o * HID + j];
        out[(bbase + b) * OUTC + o] = s;
    }
}

extern "C" void kernel_launch(void* const* d_in, const int* in_sizes, int n_in,
                              void* d_out, int out_size, void* d_ws, size_t ws_size,
                              hipStream_t stream) {
    const int*   x    = (const int*)  d_in[0];
    const float* emb  = (const float*)d_in[1];
    const float* W_ih = (const float*)d_in[2];
    const float* W_hh = (const float*)d_in[3];
    const float* b_ih = (const float*)d_in[4];
    const float* b_hh = (const float*)d_in[5];
    const float* fc_W = (const float*)d_in[6];
    const float* fc_b = (const float*)d_in[7];
    float* out = (float*)d_out;
    (void)d_ws; (void)ws_size;

    build_P<<<dim3(VOCAB * 4), dim3(256), 0, stream>>>(emb, W_ih, b_ih, b_hh);
    quant_W<<<dim3(G4), dim3(HID), 0, stream>>>(W_hh);
    lstm_chain<<<dim3(NCHAIN), dim3(512), 0, stream>>>(x, fc_W, fc_b, out);
}